// Round 1
// baseline (435.176 us; speedup 1.0000x reference)
//
#include <hip/hip_runtime.h>
#include <math.h>

#define BZ 512
#define NW 128
#define NR 256
#define DD 256

constexpr int SP    = 260;                 // padded row stride (floats) of big LDS matrix
constexpr int WSP   = 132;                 // row stride for 128x128 word_sim^T
constexpr int STG_F = 16 * 260;            // 4160 floats staging
constexpr int MISC_F = 1024;
constexpr int LDS_FLOATS = 128 * SP + STG_F + MISC_F;   // 38464 floats = 153856 B

__device__ __forceinline__ float wred_max(float v) {
#pragma unroll
  for (int m = 1; m < 64; m <<= 1) v = fmaxf(v, __shfl_xor(v, m, 64));
  return v;
}
__device__ __forceinline__ float wred_sum(float v) {
#pragma unroll
  for (int m = 1; m < 64; m <<= 1) v += __shfl_xor(v, m, 64);
  return v;
}

__global__ __launch_bounds__(256, 1) void wra_fused(
    const float* __restrict__ region, const float* __restrict__ word,
    const float* __restrict__ wattn, float* __restrict__ partial)
{
  extern __shared__ float lds[];
  float* S    = lds;                 // [128][SP]  scores -> P -> out -> word_sim^T
  float* stg  = lds + 128 * SP;      // staging tiles
  float* misc = stg + STG_F;

  const int b    = blockIdx.x;
  const int tid  = threadIdx.x;
  const int lane = tid & 63;
  const int wv   = tid >> 6;
  const int tn   = tid >> 4;   // 0..15
  const int tr   = tid & 15;   // 0..15

  const float* Rb = region + (size_t)b * NR * DD;
  const float* Wb = word   + (size_t)b * NW * DD;
  const float* Ab = wattn  + (size_t)b * NW;

  float* qa   = misc;        // [128] original attn
  float* qs   = misc + 128;  // [128] sort / clipped buffer
  float* wq   = misc + 256;  // [128] weights
  float* L1   = misc + 384;  // [128] lse_rows  (over m)
  float* L2   = misc + 512;  // [128] lse_cols  (over n)
  float* scal = misc + 640;  // [0]=low [1]=high [2]=csum

  // ---------------- Phase 0: quantile-clipped weights ----------------
  if (tid < 128) {
    float a = Ab[tid];
    qa[tid] = a;
    qs[tid] = (a != 0.0f) ? a : INFINITY;
  }
  __syncthreads();
  // bitonic sort qs[0..127] ascending (zeros -> +inf at the end)
  for (int k = 2; k <= 128; k <<= 1) {
    for (int j = k >> 1; j > 0; j >>= 1) {
      if (tid < 128) {
        int ixj = tid ^ j;
        if (ixj > tid) {
          float x = qs[tid], y = qs[ixj];
          bool up = ((tid & k) == 0);
          if (up ? (x > y) : (x < y)) { qs[tid] = y; qs[ixj] = x; }
        }
      }
      __syncthreads();
    }
  }
  if (tid == 0) {
    int nnz = 0;
    for (int i = 0; i < 128; i++) nnz += (qa[i] != 0.0f) ? 1 : 0;
    float low = 0.0f, high = 0.0f;
    if (nnz > 0) {
      float pos, frac; int lo, hi;
      pos = 0.1f * (float)(nnz - 1);
      lo = (int)floorf(pos); hi = (int)ceilf(pos);
      lo = min(max(lo, 0), 127); hi = min(max(hi, 0), 127);
      frac = pos - floorf(pos);
      low = qs[lo] * (1.0f - frac) + qs[hi] * frac;
      pos = 0.9f * (float)(nnz - 1);
      lo = (int)floorf(pos); hi = (int)ceilf(pos);
      lo = min(max(lo, 0), 127); hi = min(max(hi, 0), 127);
      frac = pos - floorf(pos);
      high = qs[lo] * (1.0f - frac) + qs[hi] * frac;
    }
    scal[0] = low; scal[1] = high;
  }
  __syncthreads();
  if (tid < 128) {
    float a = qa[tid];
    float c = (a != 0.0f) ? fminf(fmaxf(a, scal[0]), scal[1]) : 0.0f;
    qs[tid] = c;
  }
  __syncthreads();
  if (tid == 0) {
    float s = 0.0f;
    for (int i = 0; i < 128; i++) s += qs[i];
    scal[2] = s;
  }
  __syncthreads();
  if (tid < 128) wq[tid] = qs[tid] / scal[2];
  __syncthreads();

  // ---------------- Phase 1: S[n][r] = sum_d W[n][d]*R[r][d] ----------------
  float acc[8][16];
#pragma unroll
  for (int i = 0; i < 8; i++)
#pragma unroll
    for (int j = 0; j < 16; j++) acc[i][j] = 0.0f;

  float* stgW = stg;          // [8][128]  k-major
  float* stgR = stg + 1024;   // [8][256]  k-major

  for (int d0 = 0; d0 < DD; d0 += 8) {
    {
      int n = tid >> 1, k4 = (tid & 1) << 2;
      float4 v = *(const float4*)(Wb + n * DD + d0 + k4);
      stgW[(k4 + 0) * 128 + n] = v.x;
      stgW[(k4 + 1) * 128 + n] = v.y;
      stgW[(k4 + 2) * 128 + n] = v.z;
      stgW[(k4 + 3) * 128 + n] = v.w;
    }
#pragma unroll
    for (int q = 0; q < 2; q++) {
      int t = tid + q * 256;
      int r = t >> 1, k4 = (t & 1) << 2;
      float4 v = *(const float4*)(Rb + r * DD + d0 + k4);
      stgR[(k4 + 0) * 256 + r] = v.x;
      stgR[(k4 + 1) * 256 + r] = v.y;
      stgR[(k4 + 2) * 256 + r] = v.z;
      stgR[(k4 + 3) * 256 + r] = v.w;
    }
    __syncthreads();
#pragma unroll
    for (int k = 0; k < 8; k++) {
      float a[8], bb[16];
      *(float4*)&a[0] = *(float4*)&stgW[k * 128 + tn * 8];
      *(float4*)&a[4] = *(float4*)&stgW[k * 128 + tn * 8 + 4];
      *(float4*)&bb[0]  = *(float4*)&stgR[k * 256 + tr * 16];
      *(float4*)&bb[4]  = *(float4*)&stgR[k * 256 + tr * 16 + 4];
      *(float4*)&bb[8]  = *(float4*)&stgR[k * 256 + tr * 16 + 8];
      *(float4*)&bb[12] = *(float4*)&stgR[k * 256 + tr * 16 + 12];
#pragma unroll
      for (int i = 0; i < 8; i++)
#pragma unroll
        for (int j = 0; j < 16; j++)
          acc[i][j] = fmaf(a[i], bb[j], acc[i][j]);
    }
    __syncthreads();
  }
#pragma unroll
  for (int i = 0; i < 8; i++) {
    float* row = &S[(tn * 8 + i) * SP + tr * 16];
#pragma unroll
    for (int j4 = 0; j4 < 4; j4++)
      *(float4*)&row[j4 * 4] = *(float4*)&acc[i][j4 * 4];
  }
  __syncthreads();

  // ---------------- Phase 2: softmax rows (logits = S*10) ----------------
  for (int n = wv; n < NW; n += 4) {
    float v0 = S[n * SP + lane];
    float v1 = S[n * SP + lane + 64];
    float v2 = S[n * SP + lane + 128];
    float v3 = S[n * SP + lane + 192];
    float mx = wred_max(fmaxf(fmaxf(v0, v1), fmaxf(v2, v3)));
    float e0 = __expf((v0 - mx) * 10.0f);
    float e1 = __expf((v1 - mx) * 10.0f);
    float e2 = __expf((v2 - mx) * 10.0f);
    float e3 = __expf((v3 - mx) * 10.0f);
    float sm = wred_sum(e0 + e1 + e2 + e3);
    float inv = 1.0f / sm;
    S[n * SP + lane]       = e0 * inv;
    S[n * SP + lane + 64]  = e1 * inv;
    S[n * SP + lane + 128] = e2 * inv;
    S[n * SP + lane + 192] = e3 * inv;
  }
  __syncthreads();

  // ---------------- Phase 3: out[n][d] = sum_r P[n][r]*R[r][d] ----------------
  float o[8][16];
#pragma unroll
  for (int i = 0; i < 8; i++)
#pragma unroll
    for (int j = 0; j < 16; j++) o[i][j] = 0.0f;

  for (int r0 = 0; r0 < NR; r0 += 16) {
#pragma unroll
    for (int q = 0; q < 4; q++) {
      int f = tid + q * 256;          // float4 index 0..1023
      int kk = f >> 6;                // row 0..15
      int c4 = (f & 63) << 2;         // col 0..252
      float4 v = *(const float4*)(Rb + (r0 + kk) * DD + c4);
      *(float4*)&stg[kk * SP + c4] = v;
    }
    __syncthreads();
#pragma unroll
    for (int ks = 0; ks < 16; ks += 4) {
      float4 pv[8];
#pragma unroll
      for (int i = 0; i < 8; i++)
        pv[i] = *(const float4*)&S[(tn * 8 + i) * SP + r0 + ks];
#pragma unroll
      for (int k = 0; k < 4; k++) {
        float bb[16];
        *(float4*)&bb[0]  = *(float4*)&stg[(ks + k) * SP + tr * 16];
        *(float4*)&bb[4]  = *(float4*)&stg[(ks + k) * SP + tr * 16 + 4];
        *(float4*)&bb[8]  = *(float4*)&stg[(ks + k) * SP + tr * 16 + 8];
        *(float4*)&bb[12] = *(float4*)&stg[(ks + k) * SP + tr * 16 + 12];
#pragma unroll
        for (int i = 0; i < 8; i++) {
          float pk = (k == 0) ? pv[i].x : (k == 1) ? pv[i].y : (k == 2) ? pv[i].z : pv[i].w;
#pragma unroll
          for (int j = 0; j < 16; j++)
            o[i][j] = fmaf(pk, bb[j], o[i][j]);
        }
      }
    }
    __syncthreads();
  }
  // row norms (across the 16 tr-lanes sharing tn) + normalize
#pragma unroll
  for (int i = 0; i < 8; i++) {
    float ss = 0.0f;
#pragma unroll
    for (int j = 0; j < 16; j++) ss += o[i][j] * o[i][j];
#pragma unroll
    for (int m = 1; m < 16; m <<= 1) ss += __shfl_xor(ss, m, 64);
    float invn = 1.0f / fmaxf(sqrtf(ss), 1e-12f);
#pragma unroll
    for (int j = 0; j < 16; j++) o[i][j] *= invn;
  }
  // write normalized out into S area
#pragma unroll
  for (int i = 0; i < 8; i++) {
    float* row = &S[(tn * 8 + i) * SP + tr * 16];
#pragma unroll
    for (int j4 = 0; j4 < 4; j4++)
      *(float4*)&row[j4 * 4] = *(float4*)&o[i][j4 * 4];
  }
  __syncthreads();

  // ---------------- Phase 4: WS[m][n] = 10 * sum_d out[m][d]*W[n][d] ----------------
  float c3[8][8];
#pragma unroll
  for (int i = 0; i < 8; i++)
#pragma unroll
    for (int j = 0; j < 8; j++) c3[i][j] = 0.0f;

  for (int d0 = 0; d0 < DD; d0 += 8) {
    {
      int n = tid >> 1, k4 = (tid & 1) << 2;
      float4 v = *(const float4*)(Wb + n * DD + d0 + k4);
      stg[(k4 + 0) * 128 + n] = v.x;
      stg[(k4 + 1) * 128 + n] = v.y;
      stg[(k4 + 2) * 128 + n] = v.z;
      stg[(k4 + 3) * 128 + n] = v.w;
    }
    __syncthreads();
#pragma unroll
    for (int ks = 0; ks < 8; ks += 4) {
      float4 ov[8];
#pragma unroll
      for (int i = 0; i < 8; i++)
        ov[i] = *(const float4*)&S[(tn * 8 + i) * SP + d0 + ks];
#pragma unroll
      for (int k = 0; k < 4; k++) {
        float bb[8];
        *(float4*)&bb[0] = *(float4*)&stg[(ks + k) * 128 + tr * 8];
        *(float4*)&bb[4] = *(float4*)&stg[(ks + k) * 128 + tr * 8 + 4];
#pragma unroll
        for (int i = 0; i < 8; i++) {
          float vk = (k == 0) ? ov[i].x : (k == 1) ? ov[i].y : (k == 2) ? ov[i].z : ov[i].w;
#pragma unroll
          for (int j = 0; j < 8; j++)
            c3[i][j] = fmaf(vk, bb[j], c3[i][j]);
        }
      }
    }
    __syncthreads();
  }
  // write word_sim^T (scaled by 1/TEMP) into S area as WS[128][WSP]
#pragma unroll
  for (int i = 0; i < 8; i++) {
    int m = tn * 8 + i;
#pragma unroll
    for (int j = 0; j < 8; j++)
      S[m * WSP + tr * 8 + j] = c3[i][j] * 10.0f;
  }
  __syncthreads();

  // ---------------- Phase 5: logsumexps + weighted loss ----------------
  // WS[m][n] = word_sim[n][m]
  // L2[m] = lse over n (row m of WS) = lse_cols[m]
  for (int m = wv; m < 128; m += 4) {
    float v0 = S[m * WSP + lane];
    float v1 = S[m * WSP + lane + 64];
    float mx = wred_max(fmaxf(v0, v1));
    float s = __expf(v0 - mx) + __expf(v1 - mx);
    s = wred_sum(s);
    if (lane == 0) L2[m] = mx + __logf(s);
  }
  // L1[n] = lse over m (column n of WS) = lse_rows[n]
  for (int n = wv; n < 128; n += 4) {
    float v0 = S[lane * WSP + n];
    float v1 = S[(lane + 64) * WSP + n];
    float mx = wred_max(fmaxf(v0, v1));
    float s = __expf(v0 - mx) + __expf(v1 - mx);
    s = wred_sum(s);
    if (lane == 0) L1[n] = mx + __logf(s);
  }
  __syncthreads();

  if (tid < 64) {
    float t = 0.0f;
    for (int k = lane; k < 128; k += 64) {
      float dg = S[k * WSP + k];
      t += wq[k] * (L1[k] + L2[k] - 2.0f * dg);
    }
    t = wred_sum(t);
    if (lane == 0) partial[b] = t;
  }
}

__global__ void reduce_partials(const float* __restrict__ p, float* __restrict__ out) {
  __shared__ float accw[4];
  int tid = threadIdx.x;
  float t = p[tid] + p[tid + 256];
  t = wred_sum(t);
  if ((tid & 63) == 0) accw[tid >> 6] = t;
  __syncthreads();
  if (tid == 0) out[0] = (accw[0] + accw[1] + accw[2] + accw[3]) * (1.0f / 1024.0f);
}

extern "C" void kernel_launch(void* const* d_in, const int* in_sizes, int n_in,
                              void* d_out, int out_size, void* d_ws, size_t ws_size,
                              hipStream_t stream) {
  const float* region = (const float*)d_in[1];
  const float* word   = (const float*)d_in[3];
  const float* wattn  = (const float*)d_in[4];
  float* out = (float*)d_out;
  float* partial = (float*)d_ws;   // 512 floats

  size_t shmem = (size_t)LDS_FLOATS * sizeof(float);
  hipFuncSetAttribute((const void*)wra_fused,
                      hipFuncAttributeMaxDynamicSharedMemorySize, (int)shmem);
  hipLaunchKernelGGL(wra_fused, dim3(BZ), dim3(256), shmem, stream,
                     region, word, wattn, partial);
  hipLaunchKernelGGL(reduce_partials, dim3(1), dim3(256), 0, stream, partial, out);
}

// Round 2
// 326.216 us; speedup vs baseline: 1.3340x; 1.3340x over previous
//
#include <hip/hip_runtime.h>
#include <math.h>

#define BZ 512
#define NW 128
#define NR 256
#define DD 256

constexpr int SP   = 260;                 // padded row stride (floats) of big LDS matrix
constexpr int WSP  = 132;                 // row stride for 128x128 word_sim^T
constexpr int KT   = 16;                  // k-tile depth
constexpr int WST  = 20;                  // stgW row stride (row-major W tile)
constexpr int STG_F = 128 * WST + KT * 260;   // 2560 + 4160 = 6720 floats
constexpr int MISC_F = 656;
constexpr int LDS_FLOATS = 128 * SP + STG_F + MISC_F;   // 40656 floats = 162624 B

__device__ __forceinline__ float wred_max(float v) {
#pragma unroll
  for (int m = 1; m < 64; m <<= 1) v = fmaxf(v, __shfl_xor(v, m, 64));
  return v;
}
__device__ __forceinline__ float wred_sum(float v) {
#pragma unroll
  for (int m = 1; m < 64; m <<= 1) v += __shfl_xor(v, m, 64);
  return v;
}

__global__ __launch_bounds__(512, 1) void wra_fused(
    const float* __restrict__ region, const float* __restrict__ word,
    const float* __restrict__ wattn, float* __restrict__ partial)
{
  extern __shared__ float lds[];
  float* S    = lds;                 // [128][SP]  scores -> P -> out -> word_sim^T
  float* stg  = lds + 128 * SP;      // staging tiles
  float* misc = stg + STG_F;

  const int b    = blockIdx.x;
  const int tid  = threadIdx.x;
  const int lane = tid & 63;
  const int wv   = tid >> 6;   // 0..7
  const int tn   = tid >> 5;   // 0..15  (8 rows each)
  const int tr   = tid & 31;   // 0..31  (col chunks tr*4 + j4*128)

  const float* Rb = region + (size_t)b * NR * DD;
  const float* Wb = word   + (size_t)b * NW * DD;
  const float* Ab = wattn  + (size_t)b * NW;

  float* qa   = misc;        // [128] original attn
  float* qs   = misc + 128;  // [128] sort / clipped buffer
  float* wq   = misc + 256;  // [128] weights
  float* L1   = misc + 384;  // [128] lse_rows
  float* L2   = misc + 512;  // [128] lse_cols
  float* scal = misc + 640;  // [0]=low [1]=high [2]=csum

  // ---------------- Phase 0: quantile-clipped weights ----------------
  if (tid < 128) {
    float a = Ab[tid];
    qa[tid] = a;
    qs[tid] = (a != 0.0f) ? a : INFINITY;
  }
  __syncthreads();
  for (int k = 2; k <= 128; k <<= 1) {
    for (int j = k >> 1; j > 0; j >>= 1) {
      if (tid < 128) {
        int ixj = tid ^ j;
        if (ixj > tid) {
          float x = qs[tid], y = qs[ixj];
          bool up = ((tid & k) == 0);
          if (up ? (x > y) : (x < y)) { qs[tid] = y; qs[ixj] = x; }
        }
      }
      __syncthreads();
    }
  }
  if (tid == 0) {
    int nnz = 0;
    for (int i = 0; i < 128; i++) nnz += (qa[i] != 0.0f) ? 1 : 0;
    float low = 0.0f, high = 0.0f;
    if (nnz > 0) {
      float pos, frac; int lo, hi;
      pos = 0.1f * (float)(nnz - 1);
      lo = (int)floorf(pos); hi = (int)ceilf(pos);
      lo = min(max(lo, 0), 127); hi = min(max(hi, 0), 127);
      frac = pos - floorf(pos);
      low = qs[lo] * (1.0f - frac) + qs[hi] * frac;
      pos = 0.9f * (float)(nnz - 1);
      lo = (int)floorf(pos); hi = (int)ceilf(pos);
      lo = min(max(lo, 0), 127); hi = min(max(hi, 0), 127);
      frac = pos - floorf(pos);
      high = qs[lo] * (1.0f - frac) + qs[hi] * frac;
    }
    scal[0] = low; scal[1] = high;
  }
  __syncthreads();
  if (tid < 128) {
    float a = qa[tid];
    qs[tid] = (a != 0.0f) ? fminf(fmaxf(a, scal[0]), scal[1]) : 0.0f;
  }
  __syncthreads();
  if (tid == 0) {
    float s = 0.0f;
    for (int i = 0; i < 128; i++) s += qs[i];
    scal[2] = s;
  }
  __syncthreads();
  if (tid < 128) wq[tid] = qs[tid] / scal[2];
  __syncthreads();

  // ---------------- Phase 1: S[n][r] = sum_d W[n][d]*R[r][d] ----------------
  // thread (tn,tr): rows tn*8+i, cols tr*4 + j4*128 + jj
  float acc[8][8];
#pragma unroll
  for (int i = 0; i < 8; i++)
#pragma unroll
    for (int j = 0; j < 8; j++) acc[i][j] = 0.0f;

  float* stgW = stg;               // [128][WST] row-major (n, k)
  float* stgR = stg + 128 * WST;   // [KT][260]  k-major  (k, r)

  for (int d0 = 0; d0 < DD; d0 += KT) {
    {
      int n = tid >> 2, k4 = (tid & 3) << 2;
      float4 v = *(const float4*)(Wb + n * DD + d0 + k4);
      *(float4*)&stgW[n * WST + k4] = v;
    }
#pragma unroll
    for (int q = 0; q < 2; q++) {
      int f = tid + q * 512;
      int r = f >> 2, k4 = (f & 3) << 2;
      float4 v = *(const float4*)(Rb + r * DD + d0 + k4);
      stgR[(k4 + 0) * 260 + r] = v.x;
      stgR[(k4 + 1) * 260 + r] = v.y;
      stgR[(k4 + 2) * 260 + r] = v.z;
      stgR[(k4 + 3) * 260 + r] = v.w;
    }
    __syncthreads();
#pragma unroll
    for (int ks = 0; ks < KT; ks += 4) {
      float4 a4[8];
#pragma unroll
      for (int i = 0; i < 8; i++)
        a4[i] = *(const float4*)&stgW[(tn * 8 + i) * WST + ks];
#pragma unroll
      for (int k = 0; k < 4; k++) {
        float bb[8];
        *(float4*)&bb[0] = *(const float4*)&stgR[(ks + k) * 260 + tr * 4];
        *(float4*)&bb[4] = *(const float4*)&stgR[(ks + k) * 260 + tr * 4 + 128];
#pragma unroll
        for (int i = 0; i < 8; i++) {
          float ak = (k == 0) ? a4[i].x : (k == 1) ? a4[i].y : (k == 2) ? a4[i].z : a4[i].w;
#pragma unroll
          for (int j = 0; j < 8; j++)
            acc[i][j] = fmaf(ak, bb[j], acc[i][j]);
        }
      }
    }
    __syncthreads();
  }
#pragma unroll
  for (int i = 0; i < 8; i++) {
    float* row = &S[(tn * 8 + i) * SP + tr * 4];
    *(float4*)&row[0]   = *(float4*)&acc[i][0];
    *(float4*)&row[128] = *(float4*)&acc[i][4];
  }
  __syncthreads();

  // ---------------- Phase 2: softmax rows (logits = S*10) ----------------
  for (int n = wv; n < NW; n += 8) {
    float v0 = S[n * SP + lane];
    float v1 = S[n * SP + lane + 64];
    float v2 = S[n * SP + lane + 128];
    float v3 = S[n * SP + lane + 192];
    float mx = wred_max(fmaxf(fmaxf(v0, v1), fmaxf(v2, v3)));
    float e0 = __expf((v0 - mx) * 10.0f);
    float e1 = __expf((v1 - mx) * 10.0f);
    float e2 = __expf((v2 - mx) * 10.0f);
    float e3 = __expf((v3 - mx) * 10.0f);
    float sm = wred_sum(e0 + e1 + e2 + e3);
    float inv = 1.0f / sm;
    S[n * SP + lane]       = e0 * inv;
    S[n * SP + lane + 64]  = e1 * inv;
    S[n * SP + lane + 128] = e2 * inv;
    S[n * SP + lane + 192] = e3 * inv;
  }
  __syncthreads();

  // ---------------- Phase 3: out[n][d] = sum_r P[n][r]*R[r][d] ----------------
  float o[8][8];
#pragma unroll
  for (int i = 0; i < 8; i++)
#pragma unroll
    for (int j = 0; j < 8; j++) o[i][j] = 0.0f;

  float* stg3 = stg;   // [KT][260] row-major (r, d)

  for (int r0 = 0; r0 < NR; r0 += KT) {
#pragma unroll
    for (int q = 0; q < 2; q++) {
      int f = tid + q * 512;
      int rr = f >> 6;            // 0..15
      int d4 = (f & 63) << 2;     // 0..252
      *(float4*)&stg3[rr * 260 + d4] = *(const float4*)(Rb + (r0 + rr) * DD + d4);
    }
    __syncthreads();
#pragma unroll
    for (int ks = 0; ks < KT; ks += 4) {
      float4 p4[8];
#pragma unroll
      for (int i = 0; i < 8; i++)
        p4[i] = *(const float4*)&S[(tn * 8 + i) * SP + r0 + ks];
#pragma unroll
      for (int k = 0; k < 4; k++) {
        float bb[8];
        *(float4*)&bb[0] = *(const float4*)&stg3[(ks + k) * 260 + tr * 4];
        *(float4*)&bb[4] = *(const float4*)&stg3[(ks + k) * 260 + tr * 4 + 128];
#pragma unroll
        for (int i = 0; i < 8; i++) {
          float pk = (k == 0) ? p4[i].x : (k == 1) ? p4[i].y : (k == 2) ? p4[i].z : p4[i].w;
#pragma unroll
          for (int j = 0; j < 8; j++)
            o[i][j] = fmaf(pk, bb[j], o[i][j]);
        }
      }
    }
    __syncthreads();
  }
  // row norms across the 32 tr-lanes sharing tn, then normalize
#pragma unroll
  for (int i = 0; i < 8; i++) {
    float ss = 0.0f;
#pragma unroll
    for (int j = 0; j < 8; j++) ss += o[i][j] * o[i][j];
#pragma unroll
    for (int m = 1; m < 32; m <<= 1) ss += __shfl_xor(ss, m, 64);
    float invn = 1.0f / fmaxf(sqrtf(ss), 1e-12f);
#pragma unroll
    for (int j = 0; j < 8; j++) o[i][j] *= invn;
  }
#pragma unroll
  for (int i = 0; i < 8; i++) {
    float* row = &S[(tn * 8 + i) * SP + tr * 4];
    *(float4*)&row[0]   = *(float4*)&o[i][0];
    *(float4*)&row[128] = *(float4*)&o[i][4];
  }
  __syncthreads();

  // ---------------- Phase 4: WS[m][n] = 10 * sum_d out[m][d]*W[n][d] ----------------
  // thread (tn,tr): rows m=tn*8+i, cols n=tr*4+j (j<4)
  float c3[8][4];
#pragma unroll
  for (int i = 0; i < 8; i++)
#pragma unroll
    for (int j = 0; j < 4; j++) c3[i][j] = 0.0f;

  float* stgT = stg;   // [KT][132] k-major (d, n)

  for (int d0 = 0; d0 < DD; d0 += KT) {
    {
      int n = tid >> 2, k4 = (tid & 3) << 2;
      float4 v = *(const float4*)(Wb + n * DD + d0 + k4);
      stgT[(k4 + 0) * 132 + n] = v.x;
      stgT[(k4 + 1) * 132 + n] = v.y;
      stgT[(k4 + 2) * 132 + n] = v.z;
      stgT[(k4 + 3) * 132 + n] = v.w;
    }
    __syncthreads();
#pragma unroll
    for (int ks = 0; ks < KT; ks += 4) {
      float4 ov4[8];
#pragma unroll
      for (int i = 0; i < 8; i++)
        ov4[i] = *(const float4*)&S[(tn * 8 + i) * SP + d0 + ks];
#pragma unroll
      for (int k = 0; k < 4; k++) {
        float bb[4];
        *(float4*)&bb[0] = *(const float4*)&stgT[(ks + k) * 132 + tr * 4];
#pragma unroll
        for (int i = 0; i < 8; i++) {
          float vk = (k == 0) ? ov4[i].x : (k == 1) ? ov4[i].y : (k == 2) ? ov4[i].z : ov4[i].w;
#pragma unroll
          for (int j = 0; j < 4; j++)
            c3[i][j] = fmaf(vk, bb[j], c3[i][j]);
        }
      }
    }
    __syncthreads();
  }
  // write word_sim^T (scaled) into S area as WS[128][WSP]
#pragma unroll
  for (int i = 0; i < 8; i++) {
    int m = tn * 8 + i;
    float4 v;
    v.x = c3[i][0] * 10.0f; v.y = c3[i][1] * 10.0f;
    v.z = c3[i][2] * 10.0f; v.w = c3[i][3] * 10.0f;
    *(float4*)&S[m * WSP + tr * 4] = v;
  }
  __syncthreads();

  // ---------------- Phase 5: logsumexps + weighted loss ----------------
  // WS[m][n] = word_sim[n][m]
  for (int m = wv; m < 128; m += 8) {
    float v0 = S[m * WSP + lane];
    float v1 = S[m * WSP + lane + 64];
    float mx = wred_max(fmaxf(v0, v1));
    float s = __expf(v0 - mx) + __expf(v1 - mx);
    s = wred_sum(s);
    if (lane == 0) L2[m] = mx + __logf(s);
  }
  for (int n = wv; n < 128; n += 8) {
    float v0 = S[lane * WSP + n];
    float v1 = S[(lane + 64) * WSP + n];
    float mx = wred_max(fmaxf(v0, v1));
    float s = __expf(v0 - mx) + __expf(v1 - mx);
    s = wred_sum(s);
    if (lane == 0) L1[n] = mx + __logf(s);
  }
  __syncthreads();

  if (tid < 64) {
    float t = 0.0f;
    for (int k = lane; k < 128; k += 64) {
      float dg = S[k * WSP + k];
      t += wq[k] * (L1[k] + L2[k] - 2.0f * dg);
    }
    t = wred_sum(t);
    if (lane == 0) partial[b] = t;
  }
}

__global__ void reduce_partials(const float* __restrict__ p, float* __restrict__ out) {
  __shared__ float accw[4];
  int tid = threadIdx.x;
  float t = p[tid] + p[tid + 256];
  t = wred_sum(t);
  if ((tid & 63) == 0) accw[tid >> 6] = t;
  __syncthreads();
  if (tid == 0) out[0] = (accw[0] + accw[1] + accw[2] + accw[3]) * (1.0f / 1024.0f);
}

extern "C" void kernel_launch(void* const* d_in, const int* in_sizes, int n_in,
                              void* d_out, int out_size, void* d_ws, size_t ws_size,
                              hipStream_t stream) {
  const float* region = (const float*)d_in[1];
  const float* word   = (const float*)d_in[3];
  const float* wattn  = (const float*)d_in[4];
  float* out = (float*)d_out;
  float* partial = (float*)d_ws;   // 512 floats

  size_t shmem = (size_t)LDS_FLOATS * sizeof(float);
  hipFuncSetAttribute((const void*)wra_fused,
                      hipFuncAttributeMaxDynamicSharedMemorySize, (int)shmem);
  hipLaunchKernelGGL(wra_fused, dim3(BZ), dim3(512), shmem, stream,
                     region, word, wattn, partial);
  hipLaunchKernelGGL(reduce_partials, dim3(1), dim3(256), 0, stream, partial, out);
}

// Round 3
// 208.857 us; speedup vs baseline: 2.0836x; 1.5619x over previous
//
#include <hip/hip_runtime.h>
#include <math.h>

#define BZ 512
#define NW 128
#define NR 256
#define DD 256

typedef __attribute__((ext_vector_type(8))) short short8;
typedef __attribute__((ext_vector_type(4))) float f32x4;

#define MFMA(a, b, c) __builtin_amdgcn_mfma_f32_16x16x32_bf16(a, b, c, 0, 0, 0)

// LDS layout (bytes)
constexpr int PST     = 280;                    // P / out_hi row stride (bf16 units), 560B rows (16B aligned)
constexpr int P_BYTES = 128 * PST * 2;          // 71680
constexpr int STG_OFF = P_BYTES;                // staging region, 61440 B
constexpr int TS      = 40;                     // staged tile row stride (bf16), 80B rows (16B aligned)
constexpr int MISC_OFF = STG_OFF + 61440;       // 133120
constexpr int LDS_BYTES = MISC_OFF + 2624;      // 135744
constexpr int WSP = 132;                        // word_sim fp32 row stride

__device__ __forceinline__ unsigned short f2bf(float x) {
  unsigned int u = __float_as_uint(x);
  unsigned int r = (u + 0x7FFFu + ((u >> 16) & 1u)) >> 16;
  return (unsigned short)r;
}
__device__ __forceinline__ float bf2f(unsigned short h) {
  return __uint_as_float(((unsigned int)h) << 16);
}
__device__ __forceinline__ unsigned int pack2(float a, float b) {
  return (unsigned int)f2bf(a) | ((unsigned int)f2bf(b) << 16);
}
__device__ __forceinline__ unsigned int pack2lo(float a, float ha, float b, float hb) {
  return (unsigned int)f2bf(a - ha) | ((unsigned int)f2bf(b - hb) << 16);
}

__device__ __forceinline__ float wred_max(float v) {
#pragma unroll
  for (int m = 1; m < 64; m <<= 1) v = fmaxf(v, __shfl_xor(v, m, 64));
  return v;
}
__device__ __forceinline__ float wred_sum(float v) {
#pragma unroll
  for (int m = 1; m < 64; m <<= 1) v += __shfl_xor(v, m, 64);
  return v;
}
__device__ __forceinline__ float grp16_max(float v) {
#pragma unroll
  for (int m = 1; m < 16; m <<= 1) v = fmaxf(v, __shfl_xor(v, m, 64));
  return v;
}
__device__ __forceinline__ float grp16_sum(float v) {
#pragma unroll
  for (int m = 1; m < 16; m <<= 1) v += __shfl_xor(v, m, 64);
  return v;
}

__global__ __launch_bounds__(512, 1) void wra_fused(
    const float* __restrict__ region, const float* __restrict__ word,
    const float* __restrict__ wattn, float* __restrict__ partial)
{
  extern __shared__ char smem[];
  unsigned short* Pl  = (unsigned short*)smem;                 // [128][PST] bf16: P, later out_hi; later WS fp32
  unsigned short* WH  = (unsigned short*)(smem + STG_OFF);     // ph1: Whi[128][TS]
  unsigned short* WL  = (unsigned short*)(smem + STG_OFF + 10240);
  unsigned short* RH  = (unsigned short*)(smem + STG_OFF + 20480); // ph1: Rhi[256][TS]
  unsigned short* RL  = (unsigned short*)(smem + STG_OFF + 40960);
  unsigned short* RTH = (unsigned short*)(smem + STG_OFF);     // ph3: Rt hi [256 d][TS r]
  unsigned short* RTL = (unsigned short*)(smem + STG_OFF + 20480);
  float* misc = (float*)(smem + MISC_OFF);

  const int b    = blockIdx.x;
  const int tid  = threadIdx.x;
  const int lane = tid & 63;
  const int wv   = tid >> 6;   // wave 0..7
  const int l15  = lane & 15;
  const int lg   = lane >> 4;  // 0..3

  const float* Rb = region + (size_t)b * NR * DD;
  const float* Wb = word   + (size_t)b * NW * DD;
  const float* Ab = wattn  + (size_t)b * NW;

  float* qa   = misc;        // [128]
  float* qs   = misc + 128;  // [128]
  float* wq   = misc + 256;  // [128]
  float* L1   = misc + 384;  // [128]
  float* L2   = misc + 512;  // [128]
  float* scal = misc + 640;

  // ---------------- Phase 0: quantile-clipped weights ----------------
  if (tid < 128) {
    float a = Ab[tid];
    qa[tid] = a;
    qs[tid] = (a != 0.0f) ? a : INFINITY;
  }
  __syncthreads();
  for (int k = 2; k <= 128; k <<= 1) {
    for (int j = k >> 1; j > 0; j >>= 1) {
      if (tid < 128) {
        int ixj = tid ^ j;
        if (ixj > tid) {
          float x = qs[tid], y = qs[ixj];
          bool up = ((tid & k) == 0);
          if (up ? (x > y) : (x < y)) { qs[tid] = y; qs[ixj] = x; }
        }
      }
      __syncthreads();
    }
  }
  if (tid == 0) {
    int nnz = 0;
    for (int i = 0; i < 128; i++) nnz += (qa[i] != 0.0f) ? 1 : 0;
    float low = 0.0f, high = 0.0f;
    if (nnz > 0) {
      float pos, frac; int lo, hi;
      pos = 0.1f * (float)(nnz - 1);
      lo = (int)floorf(pos); hi = (int)ceilf(pos);
      lo = min(max(lo, 0), 127); hi = min(max(hi, 0), 127);
      frac = pos - floorf(pos);
      low = qs[lo] * (1.0f - frac) + qs[hi] * frac;
      pos = 0.9f * (float)(nnz - 1);
      lo = (int)floorf(pos); hi = (int)ceilf(pos);
      lo = min(max(lo, 0), 127); hi = min(max(hi, 0), 127);
      frac = pos - floorf(pos);
      high = qs[lo] * (1.0f - frac) + qs[hi] * frac;
    }
    scal[0] = low; scal[1] = high;
  }
  __syncthreads();
  if (tid < 128) {
    float a = qa[tid];
    qs[tid] = (a != 0.0f) ? fminf(fmaxf(a, scal[0]), scal[1]) : 0.0f;
  }
  __syncthreads();
  if (tid == 0) {
    float s = 0.0f;
    for (int i = 0; i < 128; i++) s += qs[i];
    scal[2] = s;
  }
  __syncthreads();
  if (tid < 128) wq[tid] = qs[tid] / scal[2];

  // ---------------- Phase 1: S = W · R^T via split-bf16 MFMA ----------------
  f32x4 acc[16];
#pragma unroll
  for (int i = 0; i < 16; i++) acc[i] = (f32x4){0.f, 0.f, 0.f, 0.f};

  const int arow = 16 * wv + l15;   // A-fragment row (this wave's output rows)
  const int koff = lg * 8;          // k offset within 32-k tile

  for (int d0 = 0; d0 < DD; d0 += 32) {
    {   // stage W[128][32] -> hi/lo bf16, row stride TS
      int row = tid >> 2, db = (tid & 3) * 8;
      const float* src = Wb + row * DD + d0 + db;
      float4 v0 = *(const float4*)(src);
      float4 v1 = *(const float4*)(src + 4);
      float x[8] = {v0.x, v0.y, v0.z, v0.w, v1.x, v1.y, v1.z, v1.w};
      unsigned int* dh = (unsigned int*)(WH + row * TS + db);
      unsigned int* dl = (unsigned int*)(WL + row * TS + db);
#pragma unroll
      for (int j = 0; j < 4; j++) {
        float a = x[2 * j], c = x[2 * j + 1];
        unsigned int h = pack2(a, c);
        dh[j] = h;
        dl[j] = pack2lo(a, bf2f((unsigned short)(h & 0xFFFF)), c, bf2f((unsigned short)(h >> 16)));
      }
    }
    {   // stage R[256][32] -> hi/lo
      int row = tid >> 1, db = (tid & 1) * 16;
      const float* src = Rb + row * DD + d0 + db;
      unsigned int* dh = (unsigned int*)(RH + row * TS + db);
      unsigned int* dl = (unsigned int*)(RL + row * TS + db);
#pragma unroll
      for (int q = 0; q < 4; q++) {
        float4 v = *(const float4*)(src + 4 * q);
        unsigned int h0 = pack2(v.x, v.y);
        unsigned int h1 = pack2(v.z, v.w);
        dh[2 * q]     = h0;
        dh[2 * q + 1] = h1;
        dl[2 * q]     = pack2lo(v.x, bf2f((unsigned short)(h0 & 0xFFFF)), v.y, bf2f((unsigned short)(h0 >> 16)));
        dl[2 * q + 1] = pack2lo(v.z, bf2f((unsigned short)(h1 & 0xFFFF)), v.w, bf2f((unsigned short)(h1 >> 16)));
      }
    }
    __syncthreads();
    short8 a_h = *(const short8*)(WH + arow * TS + koff);
    short8 a_l = *(const short8*)(WL + arow * TS + koff);
#pragma unroll
    for (int ct = 0; ct < 16; ct++) {
      const int brow = 16 * ct + l15;
      short8 b_h = *(const short8*)(RH + brow * TS + koff);
      short8 b_l = *(const short8*)(RL + brow * TS + koff);
      acc[ct] = MFMA(a_h, b_h, acc[ct]);
      acc[ct] = MFMA(a_h, b_l, acc[ct]);
      acc[ct] = MFMA(a_l, b_h, acc[ct]);
    }
    __syncthreads();
  }

  // ---------------- Phase 2: softmax in registers -> P (bf16) in LDS ----------------
#pragma unroll
  for (int reg = 0; reg < 4; reg++) {
    float mx = acc[0][reg];
#pragma unroll
    for (int ct = 1; ct < 16; ct++) mx = fmaxf(mx, acc[ct][reg]);
    mx = grp16_max(mx);
    float s = 0.f;
#pragma unroll
    for (int ct = 0; ct < 16; ct++) {
      float p = __expf((acc[ct][reg] - mx) * 10.0f);
      acc[ct][reg] = p;
      s += p;
    }
    s = grp16_sum(s);
    float inv = 1.0f / s;
    int row = 16 * wv + lg * 4 + reg;
#pragma unroll
    for (int ct = 0; ct < 16; ct++)
      Pl[row * PST + 16 * ct + l15] = f2bf(acc[ct][reg] * inv);
  }
  __syncthreads();

  // ---------------- Phase 3: out = P · R (K = r, B = R^T staged) ----------------
#pragma unroll
  for (int i = 0; i < 16; i++) acc[i] = (f32x4){0.f, 0.f, 0.f, 0.f};

  for (int r0 = 0; r0 < NR; r0 += 32) {
    {   // stage R^T tile: Rt[d=256][r=32] hi/lo
      int rl = tid >> 4;            // 0..31
      int db = tid & 15;            // 16 d's each
      const float* src = Rb + (size_t)(r0 + rl) * DD + db * 16;
      float4 v0 = *(const float4*)(src);
      float4 v1 = *(const float4*)(src + 4);
      float4 v2 = *(const float4*)(src + 8);
      float4 v3 = *(const float4*)(src + 12);
      float x[16] = {v0.x, v0.y, v0.z, v0.w, v1.x, v1.y, v1.z, v1.w,
                     v2.x, v2.y, v2.z, v2.w, v3.x, v3.y, v3.z, v3.w};
#pragma unroll
      for (int j = 0; j < 16; j++) {
        int d = db * 16 + j;
        unsigned short h = f2bf(x[j]);
        RTH[d * TS + rl] = h;
        RTL[d * TS + rl] = f2bf(x[j] - bf2f(h));
      }
    }
    __syncthreads();
    short8 p_h = *(const short8*)(Pl + arow * PST + r0 + koff);
#pragma unroll
    for (int ct = 0; ct < 16; ct++) {
      const int brow = 16 * ct + l15;
      short8 b_h = *(const short8*)(RTH + brow * TS + koff);
      short8 b_l = *(const short8*)(RTL + brow * TS + koff);
      acc[ct] = MFMA(p_h, b_h, acc[ct]);
      acc[ct] = MFMA(p_h, b_l, acc[ct]);
    }
    __syncthreads();
  }

  // normalize rows in registers, write out_hi (bf16) into Pl region
#pragma unroll
  for (int reg = 0; reg < 4; reg++) {
    float ss = 0.f;
#pragma unroll
    for (int ct = 0; ct < 16; ct++) { float v = acc[ct][reg]; ss += v * v; }
    ss = grp16_sum(ss);
    float invn = 1.0f / fmaxf(sqrtf(ss), 1e-12f);
#pragma unroll
    for (int ct = 0; ct < 16; ct++) acc[ct][reg] *= invn;
  }
  __syncthreads();   // all P reads done before overwriting Pl with out
#pragma unroll
  for (int reg = 0; reg < 4; reg++) {
    int row = 16 * wv + lg * 4 + reg;
#pragma unroll
    for (int ct = 0; ct < 16; ct++)
      Pl[row * PST + 16 * ct + l15] = f2bf(acc[ct][reg]);
  }
  __syncthreads();

  // ---------------- Phase 4: WS[m][n] = 10 * out[m]·w[n] ----------------
#pragma unroll
  for (int i = 0; i < 8; i++) acc[i] = (f32x4){0.f, 0.f, 0.f, 0.f};

  for (int d0 = 0; d0 < DD; d0 += 32) {
    {   // stage W[128][32] hi/lo (B operand)
      int row = tid >> 2, db = (tid & 3) * 8;
      const float* src = Wb + row * DD + d0 + db;
      float4 v0 = *(const float4*)(src);
      float4 v1 = *(const float4*)(src + 4);
      float x[8] = {v0.x, v0.y, v0.z, v0.w, v1.x, v1.y, v1.z, v1.w};
      unsigned int* dh = (unsigned int*)(WH + row * TS + db);
      unsigned int* dl = (unsigned int*)(WL + row * TS + db);
#pragma unroll
      for (int j = 0; j < 4; j++) {
        float a = x[2 * j], c = x[2 * j + 1];
        unsigned int h = pack2(a, c);
        dh[j] = h;
        dl[j] = pack2lo(a, bf2f((unsigned short)(h & 0xFFFF)), c, bf2f((unsigned short)(h >> 16)));
      }
    }
    __syncthreads();
    short8 a_h = *(const short8*)(Pl + arow * PST + d0 + koff);  // out_hi
#pragma unroll
    for (int ct = 0; ct < 8; ct++) {
      const int brow = 16 * ct + l15;
      short8 b_h = *(const short8*)(WH + brow * TS + koff);
      short8 b_l = *(const short8*)(WL + brow * TS + koff);
      acc[ct] = MFMA(a_h, b_h, acc[ct]);
      acc[ct] = MFMA(a_h, b_l, acc[ct]);
    }
    __syncthreads();
  }

  // write WS (fp32, stride WSP) into the Pl region
  float* WSf = (float*)Pl;
#pragma unroll
  for (int reg = 0; reg < 4; reg++) {
    int m = 16 * wv + lg * 4 + reg;
#pragma unroll
    for (int ct = 0; ct < 8; ct++)
      WSf[m * WSP + 16 * ct + l15] = acc[ct][reg] * 10.0f;
  }
  __syncthreads();

  // ---------------- Phase 5: logsumexps + weighted loss ----------------
  for (int m = wv; m < 128; m += 8) {
    float v0 = WSf[m * WSP + lane];
    float v1 = WSf[m * WSP + lane + 64];
    float mx = wred_max(fmaxf(v0, v1));
    float s = __expf(v0 - mx) + __expf(v1 - mx);
    s = wred_sum(s);
    if (lane == 0) L2[m] = mx + __logf(s);
  }
  for (int n = wv; n < 128; n += 8) {
    float v0 = WSf[lane * WSP + n];
    float v1 = WSf[(lane + 64) * WSP + n];
    float mx = wred_max(fmaxf(v0, v1));
    float s = __expf(v0 - mx) + __expf(v1 - mx);
    s = wred_sum(s);
    if (lane == 0) L1[n] = mx + __logf(s);
  }
  __syncthreads();

  if (tid < 64) {
    float t = 0.0f;
    for (int k = lane; k < 128; k += 64) {
      float dg = WSf[k * WSP + k];
      t += wq[k] * (L1[k] + L2[k] - 2.0f * dg);
    }
    t = wred_sum(t);
    if (lane == 0) partial[b] = t;
  }
}

__global__ void reduce_partials(const float* __restrict__ p, float* __restrict__ out) {
  __shared__ float accw[4];
  int tid = threadIdx.x;
  float t = p[tid] + p[tid + 256];
  t = wred_sum(t);
  if ((tid & 63) == 0) accw[tid >> 6] = t;
  __syncthreads();
  if (tid == 0) out[0] = (accw[0] + accw[1] + accw[2] + accw[3]) * (1.0f / 1024.0f);
}

extern "C" void kernel_launch(void* const* d_in, const int* in_sizes, int n_in,
                              void* d_out, int out_size, void* d_ws, size_t ws_size,
                              hipStream_t stream) {
  const float* region = (const float*)d_in[1];
  const float* word   = (const float*)d_in[3];
  const float* wattn  = (const float*)d_in[4];
  float* out = (float*)d_out;
  float* partial = (float*)d_ws;   // 512 floats

  hipFuncSetAttribute((const void*)wra_fused,
                      hipFuncAttributeMaxDynamicSharedMemorySize, LDS_BYTES);
  hipLaunchKernelGGL(wra_fused, dim3(BZ), dim3(512), LDS_BYTES, stream,
                     region, word, wattn, partial);
  hipLaunchKernelGGL(reduce_partials, dim3(1), dim3(256), 0, stream, partial, out);
}

// Round 4
// 140.847 us; speedup vs baseline: 3.0897x; 1.4829x over previous
//
#include <hip/hip_runtime.h>
#include <math.h>

#define BZ 512
#define NW 128
#define NR 256
#define DD 256

typedef __attribute__((ext_vector_type(8))) short short8;
typedef __attribute__((ext_vector_type(4))) float f32x4;

#define MFMA(a, b, c) __builtin_amdgcn_mfma_f32_16x16x32_bf16(a, b, c, 0, 0, 0)

// LDS layout (bytes)
constexpr int PST     = 280;                    // P / out_hi row stride (bf16), 560B rows
constexpr int P_BYTES = 128 * PST * 2;          // 71680
constexpr int STG_OFF = P_BYTES;
constexpr int TS      = 40;                     // staged tile row stride (bf16), 80B rows
constexpr int MISC_OFF = STG_OFF + 61440;       // 133120
constexpr int LDS_BYTES = MISC_OFF + 2624;      // 135744
constexpr int WSP = 133;                        // word_sim fp32 row stride (odd dwords)

__device__ __forceinline__ unsigned short f2bf(float x) {
  unsigned int u = __float_as_uint(x);
  unsigned int r = (u + 0x7FFFu + ((u >> 16) & 1u)) >> 16;
  return (unsigned short)r;
}
__device__ __forceinline__ float bf2f(unsigned short h) {
  return __uint_as_float(((unsigned int)h) << 16);
}

__device__ __forceinline__ void cvt8hl(const float* x, short8& h, short8& l) {
#pragma unroll
  for (int j = 0; j < 8; j++) {
    unsigned short hh = f2bf(x[j]);
    h[j] = (short)hh;
    l[j] = (short)f2bf(x[j] - bf2f(hh));
  }
}

__device__ __forceinline__ float wred_max(float v) {
#pragma unroll
  for (int m = 1; m < 64; m <<= 1) v = fmaxf(v, __shfl_xor(v, m, 64));
  return v;
}
__device__ __forceinline__ float wred_sum(float v) {
#pragma unroll
  for (int m = 1; m < 64; m <<= 1) v += __shfl_xor(v, m, 64);
  return v;
}
__device__ __forceinline__ float grp16_max(float v) {
#pragma unroll
  for (int m = 1; m < 16; m <<= 1) v = fmaxf(v, __shfl_xor(v, m, 64));
  return v;
}
__device__ __forceinline__ float grp16_sum(float v) {
#pragma unroll
  for (int m = 1; m < 16; m <<= 1) v += __shfl_xor(v, m, 64);
  return v;
}

__global__ __launch_bounds__(512, 1) void wra_fused(
    const float* __restrict__ region, const float* __restrict__ word,
    const float* __restrict__ wattn, float* __restrict__ partial)
{
  extern __shared__ char smem[];
  unsigned short* Pl  = (unsigned short*)smem;                 // [128][PST] bf16 P / out_hi; later WS fp32
  unsigned short* WH  = (unsigned short*)(smem + STG_OFF);     // ph1/ph4: Whi[128][TS]
  unsigned short* WL  = (unsigned short*)(smem + STG_OFF + 10240);
  unsigned short* RH  = (unsigned short*)(smem + STG_OFF + 20480); // ph1: Rhi[256][TS]
  unsigned short* RL  = (unsigned short*)(smem + STG_OFF + 40960);
  unsigned short* RTH = (unsigned short*)(smem + STG_OFF);     // ph3: Rt hi [256 d][TS r]
  float* misc = (float*)(smem + MISC_OFF);

  const int b    = blockIdx.x;
  const int tid  = threadIdx.x;
  const int lane = tid & 63;
  const int wv   = tid >> 6;   // wave 0..7
  const int l15  = lane & 15;
  const int lg   = lane >> 4;  // 0..3

  const float* Rb = region + (size_t)b * NR * DD;
  const float* Wb = word   + (size_t)b * NW * DD;
  const float* Ab = wattn  + (size_t)b * NW;

  float* qa   = misc;        // [128]
  float* qs   = misc + 128;  // [128]
  float* wq   = misc + 256;  // [128]
  float* L1   = misc + 384;  // [128]
  float* L2   = misc + 512;  // [128]
  float* scal = misc + 640;

  // ---------------- Phase 0: quantile-clipped weights ----------------
  if (tid < 128) {
    float a = Ab[tid];
    qa[tid] = a;
    qs[tid] = (a != 0.0f) ? a : INFINITY;
  }
  __syncthreads();
  for (int k = 2; k <= 128; k <<= 1) {
    for (int j = k >> 1; j > 0; j >>= 1) {
      if (tid < 128) {
        int ixj = tid ^ j;
        if (ixj > tid) {
          float x = qs[tid], y = qs[ixj];
          bool up = ((tid & k) == 0);
          if (up ? (x > y) : (x < y)) { qs[tid] = y; qs[ixj] = x; }
        }
      }
      __syncthreads();
    }
  }
  if (tid == 0) {
    int nnz = 0;
    for (int i = 0; i < 128; i++) nnz += (qa[i] != 0.0f) ? 1 : 0;
    float low = 0.0f, high = 0.0f;
    if (nnz > 0) {
      float pos, frac; int lo, hi;
      pos = 0.1f * (float)(nnz - 1);
      lo = (int)floorf(pos); hi = (int)ceilf(pos);
      lo = min(max(lo, 0), 127); hi = min(max(hi, 0), 127);
      frac = pos - floorf(pos);
      low = qs[lo] * (1.0f - frac) + qs[hi] * frac;
      pos = 0.9f * (float)(nnz - 1);
      lo = (int)floorf(pos); hi = (int)ceilf(pos);
      lo = min(max(lo, 0), 127); hi = min(max(hi, 0), 127);
      frac = pos - floorf(pos);
      high = qs[lo] * (1.0f - frac) + qs[hi] * frac;
    }
    scal[0] = low; scal[1] = high;
  }
  __syncthreads();
  if (tid < 128) {
    float a = qa[tid];
    qs[tid] = (a != 0.0f) ? fminf(fmaxf(a, scal[0]), scal[1]) : 0.0f;
  }
  __syncthreads();
  if (tid == 0) {
    float s = 0.0f;
    for (int i = 0; i < 128; i++) s += qs[i];
    scal[2] = s;
  }
  __syncthreads();
  if (tid < 128) wq[tid] = qs[tid] / scal[2];

  // ---------------- Phase 1: S = W · R^T via split-bf16 MFMA ----------------
  f32x4 acc[16];
#pragma unroll
  for (int i = 0; i < 16; i++) acc[i] = (f32x4){0.f, 0.f, 0.f, 0.f};

  const int arow = 16 * wv + l15;   // this wave's output rows
  const int koff = lg * 8;          // k offset within 32-k tile

  for (int d0 = 0; d0 < DD; d0 += 32) {
    {   // stage W[128][32] -> hi/lo bf16
      int row = tid >> 2, db = (tid & 3) * 8;
      const float* src = Wb + row * DD + d0 + db;
      float x[8];
      *(float4*)&x[0] = *(const float4*)(src);
      *(float4*)&x[4] = *(const float4*)(src + 4);
      short8 h, l;
      cvt8hl(x, h, l);
      *(short8*)(WH + row * TS + db) = h;
      *(short8*)(WL + row * TS + db) = l;
    }
    {   // stage R[256][32] -> hi/lo
      int row = tid >> 1, db = (tid & 1) * 16;
      const float* src = Rb + row * DD + d0 + db;
      float x[16];
#pragma unroll
      for (int q = 0; q < 4; q++) *(float4*)&x[4 * q] = *(const float4*)(src + 4 * q);
      short8 h0, l0, h1, l1;
      cvt8hl(x, h0, l0);
      cvt8hl(x + 8, h1, l1);
      *(short8*)(RH + row * TS + db)     = h0;
      *(short8*)(RH + row * TS + db + 8) = h1;
      *(short8*)(RL + row * TS + db)     = l0;
      *(short8*)(RL + row * TS + db + 8) = l1;
    }
    __syncthreads();
    short8 a_h = *(const short8*)(WH + arow * TS + koff);
    short8 a_l = *(const short8*)(WL + arow * TS + koff);
#pragma unroll
    for (int ct = 0; ct < 16; ct++) {
      const int brow = 16 * ct + l15;
      short8 b_h = *(const short8*)(RH + brow * TS + koff);
      short8 b_l = *(const short8*)(RL + brow * TS + koff);
      acc[ct] = MFMA(a_h, b_h, acc[ct]);
      acc[ct] = MFMA(a_h, b_l, acc[ct]);
      acc[ct] = MFMA(a_l, b_h, acc[ct]);
    }
    __syncthreads();
  }

  // ---------------- Phase 2: softmax in registers -> P (bf16) in LDS ----------------
#pragma unroll
  for (int reg = 0; reg < 4; reg++) {
    float mx = acc[0][reg];
#pragma unroll
    for (int ct = 1; ct < 16; ct++) mx = fmaxf(mx, acc[ct][reg]);
    mx = grp16_max(mx);
    float s = 0.f;
#pragma unroll
    for (int ct = 0; ct < 16; ct++) {
      float p = __expf((acc[ct][reg] - mx) * 10.0f);
      acc[ct][reg] = p;
      s += p;
    }
    s = grp16_sum(s);
    float inv = 1.0f / s;
    int row = 16 * wv + lg * 4 + reg;
#pragma unroll
    for (int ct = 0; ct < 16; ct++)
      Pl[row * PST + 16 * ct + l15] = f2bf(acc[ct][reg] * inv);
  }
  __syncthreads();

  // ---------------- Phase 3: out = P · R (B = R^T, hi-only) ----------------
#pragma unroll
  for (int i = 0; i < 16; i++) acc[i] = (f32x4){0.f, 0.f, 0.f, 0.f};

  for (int r0 = 0; r0 < NR; r0 += 32) {
    // stage Rt[d=0..255][32 r] hi: lane owns one d (coalesced column reads),
    // writes one aligned 16B chunk -> conflict-free
#pragma unroll
    for (int t = 0; t < 2; t++) {
      int idx = tid + t * 512;
      int d = idx & 255, rc = idx >> 8;
      const float* src = Rb + (size_t)(r0 + rc * 8) * DD + d;
      short8 h;
#pragma unroll
      for (int i = 0; i < 8; i++) h[i] = (short)f2bf(src[i * DD]);
      *(short8*)(RTH + d * TS + rc * 8) = h;
    }
    __syncthreads();
    short8 p_h = *(const short8*)(Pl + arow * PST + r0 + koff);
#pragma unroll
    for (int ct = 0; ct < 16; ct++) {
      const int brow = 16 * ct + l15;
      short8 b_h = *(const short8*)(RTH + brow * TS + koff);
      acc[ct] = MFMA(p_h, b_h, acc[ct]);
    }
    __syncthreads();
  }

  // normalize rows in registers, write out_hi (bf16) into Pl region
#pragma unroll
  for (int reg = 0; reg < 4; reg++) {
    float ss = 0.f;
#pragma unroll
    for (int ct = 0; ct < 16; ct++) { float v = acc[ct][reg]; ss += v * v; }
    ss = grp16_sum(ss);
    float invn = 1.0f / fmaxf(sqrtf(ss), 1e-12f);
#pragma unroll
    for (int ct = 0; ct < 16; ct++) acc[ct][reg] *= invn;
  }
  __syncthreads();   // all P reads done before overwriting Pl with out
#pragma unroll
  for (int reg = 0; reg < 4; reg++) {
    int row = 16 * wv + lg * 4 + reg;
#pragma unroll
    for (int ct = 0; ct < 16; ct++)
      Pl[row * PST + 16 * ct + l15] = f2bf(acc[ct][reg]);
  }
  __syncthreads();

  // ---------------- Phase 4: WS[m][n] = 10 * out[m]·w[n] (hi-only W) ----------------
#pragma unroll
  for (int i = 0; i < 8; i++) acc[i] = (f32x4){0.f, 0.f, 0.f, 0.f};

  for (int d0 = 0; d0 < DD; d0 += 32) {
    {   // stage W[128][32] hi
      int row = tid >> 2, db = (tid & 3) * 8;
      const float* src = Wb + row * DD + d0 + db;
      float x[8];
      *(float4*)&x[0] = *(const float4*)(src);
      *(float4*)&x[4] = *(const float4*)(src + 4);
      short8 h;
#pragma unroll
      for (int j = 0; j < 8; j++) h[j] = (short)f2bf(x[j]);
      *(short8*)(WH + row * TS + db) = h;
    }
    __syncthreads();
    short8 a_h = *(const short8*)(Pl + arow * PST + d0 + koff);  // out_hi
#pragma unroll
    for (int ct = 0; ct < 8; ct++) {
      const int brow = 16 * ct + l15;
      short8 b_h = *(const short8*)(WH + brow * TS + koff);
      acc[ct] = MFMA(a_h, b_h, acc[ct]);
    }
    __syncthreads();
  }

  // write WS (fp32, stride WSP) into the Pl region
  float* WSf = (float*)Pl;
#pragma unroll
  for (int reg = 0; reg < 4; reg++) {
    int m = 16 * wv + lg * 4 + reg;
#pragma unroll
    for (int ct = 0; ct < 8; ct++)
      WSf[m * WSP + 16 * ct + l15] = acc[ct][reg] * 10.0f;
  }
  __syncthreads();

  // ---------------- Phase 5: logsumexps + weighted loss ----------------
  for (int m = wv; m < 128; m += 8) {
    float v0 = WSf[m * WSP + lane];
    float v1 = WSf[m * WSP + lane + 64];
    float mx = wred_max(fmaxf(v0, v1));
    float s = __expf(v0 - mx) + __expf(v1 - mx);
    s = wred_sum(s);
    if (lane == 0) L2[m] = mx + __logf(s);
  }
  for (int n = wv; n < 128; n += 8) {
    float v0 = WSf[lane * WSP + n];
    float v1 = WSf[(lane + 64) * WSP + n];
    float mx = wred_max(fmaxf(v0, v1));
    float s = __expf(v0 - mx) + __expf(v1 - mx);
    s = wred_sum(s);
    if (lane == 0) L1[n] = mx + __logf(s);
  }
  __syncthreads();

  if (tid < 64) {
    float t = 0.0f;
    for (int k = lane; k < 128; k += 64) {
      float dg = WSf[k * WSP + k];
      t += wq[k] * (L1[k] + L2[k] - 2.0f * dg);
    }
    t = wred_sum(t);
    if (lane == 0) partial[b] = t;
  }
}

__global__ void reduce_partials(const float* __restrict__ p, float* __restrict__ out) {
  __shared__ float accw[4];
  int tid = threadIdx.x;
  float t = p[tid] + p[tid + 256];
  t = wred_sum(t);
  if ((tid & 63) == 0) accw[tid >> 6] = t;
  __syncthreads();
  if (tid == 0) out[0] = (accw[0] + accw[1] + accw[2] + accw[3]) * (1.0f / 1024.0f);
}

extern "C" void kernel_launch(void* const* d_in, const int* in_sizes, int n_in,
                              void* d_out, int out_size, void* d_ws, size_t ws_size,
                              hipStream_t stream) {
  const float* region = (const float*)d_in[1];
  const float* word   = (const float*)d_in[3];
  const float* wattn  = (const float*)d_in[4];
  float* out = (float*)d_out;
  float* partial = (float*)d_ws;   // 512 floats

  hipFuncSetAttribute((const void*)wra_fused,
                      hipFuncAttributeMaxDynamicSharedMemorySize, LDS_BYTES);
  hipLaunchKernelGGL(wra_fused, dim3(BZ), dim3(512), LDS_BYTES, stream,
                     region, word, wattn, partial);
  hipLaunchKernelGGL(reduce_partials, dim3(1), dim3(256), 0, stream, partial, out);
}

// Round 5
// 114.053 us; speedup vs baseline: 3.8156x; 1.2349x over previous
//
#include <hip/hip_runtime.h>
#include <hip/hip_bf16.h>
#include <math.h>

#define BZ 512
#define NW 128
#define NR 256
#define DD 256

typedef __attribute__((ext_vector_type(8))) short short8;
typedef __attribute__((ext_vector_type(4))) float f32x4;

#define MFMA(a, b, c) __builtin_amdgcn_mfma_f32_16x16x32_bf16(a, b, c, 0, 0, 0)

// LDS layout (bytes)
constexpr int PST      = 280;                   // P / out_hi row stride (bf16), 560B rows
constexpr int P_BYTES  = 128 * PST * 2;         // 71680
constexpr int STG_OFF  = P_BYTES;
constexpr int TS       = 40;                    // staged tile row stride (bf16), 80B rows
constexpr int STG_BYTES = 2 * 40960;            // phase-1 double buffer (superset of ph3/ph4)
constexpr int MISC_OFF = STG_OFF + STG_BYTES;   // 153600
constexpr int LDS_BYTES = MISC_OFF + 2624;      // 156224
constexpr int WSP = 133;                        // word_sim fp32 row stride (odd dwords)

union BF2U { __hip_bfloat162 h; unsigned int u; };
__device__ __forceinline__ unsigned int pkbf(float a, float b) {
  BF2U c; c.h = __float22bfloat162_rn(make_float2(a, b));
  return c.u;
}
union U4S8 { unsigned int u[4]; short8 s; };
__device__ __forceinline__ short8 cvt_h8(const float* x) {
  U4S8 r;
#pragma unroll
  for (int j = 0; j < 4; j++) r.u[j] = pkbf(x[2*j], x[2*j+1]);
  return r.s;
}
__device__ __forceinline__ void cvt_hl8(const float* x, short8* h, short8* l) {
  U4S8 rh, rl;
#pragma unroll
  for (int j = 0; j < 4; j++) rh.u[j] = pkbf(x[2*j], x[2*j+1]);
#pragma unroll
  for (int j = 0; j < 4; j++) {
    float la = x[2*j]   - __uint_as_float(rh.u[j] << 16);
    float lb = x[2*j+1] - __uint_as_float(rh.u[j] & 0xFFFF0000u);
    rl.u[j] = pkbf(la, lb);
  }
  *h = rh.s; *l = rl.s;
}
__device__ __forceinline__ unsigned short f2bf(float x) {
  unsigned int u = __float_as_uint(x);
  unsigned int r = (u + 0x7FFFu + ((u >> 16) & 1u)) >> 16;
  return (unsigned short)r;
}

__device__ __forceinline__ float wred_max(float v) {
#pragma unroll
  for (int m = 1; m < 64; m <<= 1) v = fmaxf(v, __shfl_xor(v, m, 64));
  return v;
}
__device__ __forceinline__ float wred_sum(float v) {
#pragma unroll
  for (int m = 1; m < 64; m <<= 1) v += __shfl_xor(v, m, 64);
  return v;
}
__device__ __forceinline__ float grp16_max(float v) {
#pragma unroll
  for (int m = 1; m < 16; m <<= 1) v = fmaxf(v, __shfl_xor(v, m, 64));
  return v;
}
__device__ __forceinline__ float grp16_sum(float v) {
#pragma unroll
  for (int m = 1; m < 16; m <<= 1) v += __shfl_xor(v, m, 64);
  return v;
}

__global__ __launch_bounds__(512, 1) void wra_fused(
    const float* __restrict__ region, const float* __restrict__ word,
    const float* __restrict__ wattn, float* __restrict__ partial)
{
  extern __shared__ char smem[];
  unsigned short* Pl = (unsigned short*)smem;       // [128][PST] bf16 P / out_hi; later WS fp32
  char* STG = smem + STG_OFF;
  float* misc = (float*)(smem + MISC_OFF);

  const int b    = blockIdx.x;
  const int tid  = threadIdx.x;
  const int lane = tid & 63;
  const int wv   = tid >> 6;   // wave 0..7
  const int l15  = lane & 15;
  const int lg   = lane >> 4;  // 0..3

  const float* Rb = region + (size_t)b * NR * DD;
  const float* Wb = word   + (size_t)b * NW * DD;
  const float* Ab = wattn  + (size_t)b * NW;

  float* qa   = misc;        // [128]
  float* qs   = misc + 128;  // [128]
  float* wq   = misc + 256;  // [128]
  float* L1   = misc + 384;  // [128]
  float* L2   = misc + 512;  // [128]
  float* scal = misc + 640;

  const int arow = 16 * wv + l15;   // this wave's output rows (A-frag row)
  const int koff = lg * 8;          // k offset within 32-k tile

  // staging thread mappings
  const int r_row = tid >> 1;          // phase-1 R: 0..255
  const int r_db  = (tid & 1) * 16;    // 0 / 16
  const int rt_d  = tid & 255;         // phase-3 RT
  const int rt_rc = tid >> 8;          // 0 / 1
  const int w4row = tid >> 2;          // phase-4 W: 0..127
  const int w4db  = (tid & 3) * 8;

  float rx[16], wx1[8], rx3[16], wx4[8];

  auto RH_BUF = [&](int p) { return (unsigned short*)(STG + p * 40960); };
  auto RL_BUF = [&](int p) { return (unsigned short*)(STG + p * 40960 + 20480); };
  auto RT_BUF = [&](int p) { return (unsigned short*)(STG + p * 20480); };
  auto W4_BUF = [&](int p) { return (unsigned short*)(STG + p * 10240); };

  auto load_R = [&](int d0) {
    const float* src = Rb + r_row * DD + d0 + r_db;
#pragma unroll
    for (int q = 0; q < 4; q++) *(float4*)&rx[4*q] = *(const float4*)(src + 4*q);
  };
  auto load_W1 = [&](int d0) {
    const float* src = Wb + arow * DD + d0 + koff;
    *(float4*)&wx1[0] = *(const float4*)(src);
    *(float4*)&wx1[4] = *(const float4*)(src + 4);
  };
  auto stage_R = [&](int p) {
    short8 h0, l0, h1, l1;
    cvt_hl8(rx, &h0, &l0);
    cvt_hl8(rx + 8, &h1, &l1);
    unsigned short* RHp = RH_BUF(p);
    unsigned short* RLp = RL_BUF(p);
    *(short8*)(RHp + r_row * TS + r_db)     = h0;
    *(short8*)(RHp + r_row * TS + r_db + 8) = h1;
    *(short8*)(RLp + r_row * TS + r_db)     = l0;
    *(short8*)(RLp + r_row * TS + r_db + 8) = l1;
  };
  auto load_RT = [&](int r0) {
#pragma unroll
    for (int g = 0; g < 2; g++) {
      const float* src = Rb + (size_t)(r0 + (rt_rc + 2 * g) * 8) * DD + rt_d;
#pragma unroll
      for (int i = 0; i < 8; i++) rx3[8 * g + i] = src[i * DD];
    }
  };
  auto stage_RT = [&](int p) {
    unsigned short* RTp = RT_BUF(p);
    short8 h0 = cvt_h8(rx3), h1 = cvt_h8(rx3 + 8);
    *(short8*)(RTp + rt_d * TS + rt_rc * 8)       = h0;
    *(short8*)(RTp + rt_d * TS + (rt_rc + 2) * 8) = h1;
  };
  auto load_W4 = [&](int d0) {
    const float* src = Wb + w4row * DD + d0 + w4db;
    *(float4*)&wx4[0] = *(const float4*)(src);
    *(float4*)&wx4[4] = *(const float4*)(src + 4);
  };
  auto stage_W4 = [&](int p) {
    *(short8*)(W4_BUF(p) + w4row * TS + w4db) = cvt_h8(wx4);
  };

  // issue phase-1 tile-0 loads immediately (hidden under phase 0)
  load_W1(0);
  load_R(0);

  // ---------------- Phase 0: quantile-clipped weights ----------------
  if (tid < 128) {
    float a = Ab[tid];
    qa[tid] = a;
    qs[tid] = (a != 0.0f) ? a : INFINITY;
  }
  __syncthreads();
  for (int k = 2; k <= 128; k <<= 1) {
    for (int j = k >> 1; j > 0; j >>= 1) {
      if (tid < 128) {
        int ixj = tid ^ j;
        if (ixj > tid) {
          float x = qs[tid], y = qs[ixj];
          bool up = ((tid & k) == 0);
          if (up ? (x > y) : (x < y)) { qs[tid] = y; qs[ixj] = x; }
        }
      }
      __syncthreads();
    }
  }
  if (tid < 64) {
    int c = ((qa[lane] != 0.0f) ? 1 : 0) + ((qa[lane + 64] != 0.0f) ? 1 : 0);
#pragma unroll
    for (int m = 1; m < 64; m <<= 1) c += __shfl_xor(c, m, 64);
    if (lane == 0) {
      int nnz = c;
      float low = 0.0f, high = 0.0f;
      if (nnz > 0) {
        float pos = 0.1f * (float)(nnz - 1);
        int lo = (int)floorf(pos), hi = (int)ceilf(pos);
        float frac = pos - floorf(pos);
        low = qs[lo] * (1.0f - frac) + qs[hi] * frac;
        pos = 0.9f * (float)(nnz - 1);
        lo = (int)floorf(pos); hi = (int)ceilf(pos);
        frac = pos - floorf(pos);
        high = qs[lo] * (1.0f - frac) + qs[hi] * frac;
      }
      scal[0] = low; scal[1] = high;
    }
  }
  __syncthreads();
  if (tid < 128) {
    float a = qa[tid];
    qs[tid] = (a != 0.0f) ? fminf(fmaxf(a, scal[0]), scal[1]) : 0.0f;
  }
  __syncthreads();
  if (tid < 64) {
    float s = qs[lane] + qs[lane + 64];
    s = wred_sum(s);
    if (lane == 0) scal[2] = s;
  }
  __syncthreads();
  if (tid < 128) wq[tid] = qs[tid] / scal[2];

  // ---------------- Phase 1: S = W · R^T (split-bf16, 3 MFMA) ----------------
  f32x4 acc[16];
#pragma unroll
  for (int i = 0; i < 16; i++) acc[i] = (f32x4){0.f, 0.f, 0.f, 0.f};

  stage_R(0);            // tile 0 -> buf0 (consumes rx = R(0))
  load_R(32);            // issue R(1)
  __syncthreads();       // buf0 ready (also covers wq writes)

#pragma unroll 2
  for (int t = 0; t < 8; t++) {
    const int p = t & 1;
    short8 a_h, a_l;
    cvt_hl8(wx1, &a_h, &a_l);                 // consume W(t)
    if (t < 7) {
      stage_R(p ^ 1);                         // consume R(t+1) -> buf p^1
      load_W1((t + 1) * 32);                  // issue W(t+1)
      if (t < 6) load_R((t + 2) * 32);        // issue R(t+2)
    }
    unsigned short* RHp = RH_BUF(p);
    unsigned short* RLp = RL_BUF(p);
#pragma unroll
    for (int ct = 0; ct < 16; ct++) {
      const int brow = 16 * ct + l15;
      short8 b_h = *(const short8*)(RHp + brow * TS + koff);
      short8 b_l = *(const short8*)(RLp + brow * TS + koff);
      acc[ct] = MFMA(a_h, b_h, acc[ct]);
      acc[ct] = MFMA(a_h, b_l, acc[ct]);
      acc[ct] = MFMA(a_l, b_h, acc[ct]);
    }
    __syncthreads();
  }

  // ---------------- Phase 2: softmax in registers -> P (bf16) ----------------
  load_RT(0);   // prefetch phase-3 tile 0 under softmax
#pragma unroll
  for (int reg = 0; reg < 4; reg++) {
    float mx = acc[0][reg];
#pragma unroll
    for (int ct = 1; ct < 16; ct++) mx = fmaxf(mx, acc[ct][reg]);
    mx = grp16_max(mx);
    float s = 0.f;
#pragma unroll
    for (int ct = 0; ct < 16; ct++) {
      float p = __expf((acc[ct][reg] - mx) * 10.0f);
      acc[ct][reg] = p;
      s += p;
    }
    s = grp16_sum(s);
    float inv = 1.0f / s;
    int row = 16 * wv + lg * 4 + reg;
#pragma unroll
    for (int ct = 0; ct < 16; ct++)
      Pl[row * PST + 16 * ct + l15] = f2bf(acc[ct][reg] * inv);
  }

  // ---------------- Phase 3: out = P · R (B = R^T, hi-only) ----------------
#pragma unroll
  for (int i = 0; i < 16; i++) acc[i] = (f32x4){0.f, 0.f, 0.f, 0.f};

  stage_RT(0);
  load_RT(32);
  __syncthreads();   // covers P writes + RT buf0

#pragma unroll 2
  for (int t = 0; t < 8; t++) {
    const int p = t & 1;
    short8 p_h = *(const short8*)(Pl + arow * PST + t * 32 + koff);
    if (t < 7) {
      stage_RT(p ^ 1);
      if (t < 6) load_RT((t + 2) * 32);
    }
    unsigned short* RTp = RT_BUF(p);
#pragma unroll
    for (int ct = 0; ct < 16; ct++) {
      short8 b_h = *(const short8*)(RTp + (16 * ct + l15) * TS + koff);
      acc[ct] = MFMA(p_h, b_h, acc[ct]);
    }
    __syncthreads();
  }

  // normalize rows in registers; write out_hi into Pl
  load_W4(0);   // prefetch phase-4 tile 0 under normalize
#pragma unroll
  for (int reg = 0; reg < 4; reg++) {
    float ss = 0.f;
#pragma unroll
    for (int ct = 0; ct < 16; ct++) { float v = acc[ct][reg]; ss += v * v; }
    ss = grp16_sum(ss);
    float invn = 1.0f / fmaxf(sqrtf(ss), 1e-12f);
#pragma unroll
    for (int ct = 0; ct < 16; ct++) acc[ct][reg] *= invn;
  }
#pragma unroll
  for (int reg = 0; reg < 4; reg++) {
    int row = 16 * wv + lg * 4 + reg;
#pragma unroll
    for (int ct = 0; ct < 16; ct++)
      Pl[row * PST + 16 * ct + l15] = f2bf(acc[ct][reg]);
  }

  // ---------------- Phase 4: WS[m][n] = 10 * out[m]·w[n] (hi-only) ----------------
#pragma unroll
  for (int i = 0; i < 8; i++) acc[i] = (f32x4){0.f, 0.f, 0.f, 0.f};

  stage_W4(0);
  load_W4(32);
  __syncthreads();   // covers out writes + W buf0

#pragma unroll 2
  for (int t = 0; t < 8; t++) {
    const int p = t & 1;
    short8 a_h = *(const short8*)(Pl + arow * PST + t * 32 + koff);
    if (t < 7) {
      stage_W4(p ^ 1);
      if (t < 6) load_W4((t + 2) * 32);
    }
    unsigned short* WHp = W4_BUF(p);
#pragma unroll
    for (int ct = 0; ct < 8; ct++) {
      short8 b_h = *(const short8*)(WHp + (16 * ct + l15) * TS + koff);
      acc[ct] = MFMA(a_h, b_h, acc[ct]);
    }
    __syncthreads();
  }

  // write WS (fp32, stride WSP) into the Pl region
  float* WSf = (float*)Pl;
#pragma unroll
  for (int reg = 0; reg < 4; reg++) {
    int m = 16 * wv + lg * 4 + reg;
#pragma unroll
    for (int ct = 0; ct < 8; ct++)
      WSf[m * WSP + 16 * ct + l15] = acc[ct][reg] * 10.0f;
  }
  __syncthreads();

  // ---------------- Phase 5: logsumexps + weighted loss ----------------
  for (int m = wv; m < 128; m += 8) {
    float v0 = WSf[m * WSP + lane];
    float v1 = WSf[m * WSP + lane + 64];
    float mx = wred_max(fmaxf(v0, v1));
    float s = __expf(v0 - mx) + __expf(v1 - mx);
    s = wred_sum(s);
    if (lane == 0) L2[m] = mx + __logf(s);
  }
  for (int n = wv; n < 128; n += 8) {
    float v0 = WSf[lane * WSP + n];
    float v1 = WSf[(lane + 64) * WSP + n];
    float mx = wred_max(fmaxf(v0, v1));
    float s = __expf(v0 - mx) + __expf(v1 - mx);
    s = wred_sum(s);
    if (lane == 0) L1[n] = mx + __logf(s);
  }
  __syncthreads();

  if (tid < 64) {
    float t = 0.0f;
    for (int k = lane; k < 128; k += 64) {
      float dg = WSf[k * WSP + k];
      t += wq[k] * (L1[k] + L2[k] - 2.0f * dg);
    }
    t = wred_sum(t);
    if (lane == 0) partial[b] = t;
  }
}

__global__ void reduce_partials(const float* __restrict__ p, float* __restrict__ out) {
  __shared__ float accw[4];
  int tid = threadIdx.x;
  float t = p[tid] + p[tid + 256];
  t = wred_sum(t);
  if ((tid & 63) == 0) accw[tid >> 6] = t;
  __syncthreads();
  if (tid == 0) out[0] = (accw[0] + accw[1] + accw[2] + accw[3]) * (1.0f / 1024.0f);
}

extern "C" void kernel_launch(void* const* d_in, const int* in_sizes, int n_in,
                              void* d_out, int out_size, void* d_ws, size_t ws_size,
                              hipStream_t stream) {
  const float* region = (const float*)d_in[1];
  const float* word   = (const float*)d_in[3];
  const float* wattn  = (const float*)d_in[4];
  float* out = (float*)d_out;
  float* partial = (float*)d_ws;   // 512 floats

  hipFuncSetAttribute((const void*)wra_fused,
                      hipFuncAttributeMaxDynamicSharedMemorySize, LDS_BYTES);
  hipLaunchKernelGGL(wra_fused, dim3(BZ), dim3(512), LDS_BYTES, stream,
                     region, word, wattn, partial);
  hipLaunchKernelGGL(reduce_partials, dim3(1), dim3(256), 0, stream, partial, out);
}

// Round 7
// 73.779 us; speedup vs baseline: 5.8984x; 1.5459x over previous
//
#include <hip/hip_runtime.h>
#include <math.h>

#define BZ 512
#define NW 128
#define NR 256
#define DD 256

typedef _Float16 half8 __attribute__((ext_vector_type(8)));
typedef __fp16 fp16x2 __attribute__((ext_vector_type(2)));
typedef __attribute__((ext_vector_type(4))) float f32x4;

#define MFMA16(a, b, c) __builtin_amdgcn_mfma_f32_16x16x32_f16(a, b, c, 0, 0, 0)

// ---- LDS layout (bytes) ----
constexpr int TS      = 40;       // staged tile row stride (u16 units), 80 B rows
constexpr int BUFB    = 20480;    // one staging buffer
constexpr int TB_OFF  = 40960;    // per-wave transpose buffers: 8 waves x 2 x 1280 B
constexpr int TBS     = 40;       // TB row stride (u16)
constexpr int MISC_OFF = 61440;
constexpr int LDS_BYTES = MISC_OFF + 3200;   // 64640

union PK2 { fp16x2 h; unsigned int u; };
__device__ __forceinline__ unsigned int pkh(float a, float b) {
  PK2 c; c.h = __builtin_amdgcn_cvt_pkrtz(a, b);
  return c.u;
}
union U8H { unsigned int u[4]; half8 v; };

__device__ __forceinline__ float wred_sum(float v) {
#pragma unroll
  for (int m = 1; m < 64; m <<= 1) v += __shfl_xor(v, m, 64);
  return v;
}
__device__ __forceinline__ float grp16_max(float v) {
#pragma unroll
  for (int m = 1; m < 16; m <<= 1) v = fmaxf(v, __shfl_xor(v, m, 64));
  return v;
}
__device__ __forceinline__ float grp16_sum(float v) {
#pragma unroll
  for (int m = 1; m < 16; m <<= 1) v += __shfl_xor(v, m, 64);
  return v;
}

__global__ __launch_bounds__(512, 4) void wra_fused(
    const float* __restrict__ region, const float* __restrict__ word,
    const float* __restrict__ wattn, float* __restrict__ partial)
{
  extern __shared__ char smem[];
  float* misc = (float*)(smem + MISC_OFF);
  float* PMX  = (float*)smem;              // phase-5 only (staging dead by then)
  float* PSM  = (float*)(smem + 4096);

  const int b    = blockIdx.x;
  const int tid  = threadIdx.x;
  const int lane = tid & 63;
  const int wv   = tid >> 6;   // 0..7
  const int l15  = lane & 15;
  const int lg   = lane >> 4;  // 0..3

  const float* Rb = region + (size_t)b * NR * DD;
  const float* Wb = word   + (size_t)b * NW * DD;
  const float* Ab = wattn  + (size_t)b * NW;

  float* qa   = misc;        // [128]
  float* qs   = misc + 128;  // [128]
  float* wq   = misc + 256;  // [128]
  float* L1   = misc + 384;  // [128]
  float* L2   = misc + 512;  // [128]
  float* dgA  = misc + 640;  // [128]
  float* scal = misc + 768;

  unsigned short* TBb = (unsigned short*)(smem + TB_OFF) + wv * 1280;  // 2 x 640 u16

  const int arow = 16 * wv + l15;
  const int koff = lg * 8;

  // staging thread maps
  const int r_row = tid >> 1;          // ph1 R: 0..255
  const int r_db  = (tid & 1) * 16;
  const int rt_d  = tid & 255;         // ph3 RT
  const int rt_rc = tid >> 8;          // 0/1
  const int w4row = tid >> 2;          // ph4 W: 0..127
  const int w4db  = (tid & 3) * 8;

  float rx[16], wx1[8], rx3[16], wx4[8];

  auto SBUF = [&](int p) { return (unsigned short*)(smem + p * BUFB); };

  auto load_R = [&](int d0) {
    const float* src = Rb + r_row * DD + d0 + r_db;
#pragma unroll
    for (int q = 0; q < 4; q++) *(float4*)&rx[4*q] = *(const float4*)(src + 4*q);
  };
  auto stage_R = [&](int p) {
    U8H h0, h1;
#pragma unroll
    for (int j = 0; j < 4; j++) h0.u[j] = pkh(rx[2*j],   rx[2*j+1]);
#pragma unroll
    for (int j = 0; j < 4; j++) h1.u[j] = pkh(rx[8+2*j], rx[9+2*j]);
    *(half8*)(SBUF(p) + r_row * TS + r_db)     = h0.v;
    *(half8*)(SBUF(p) + r_row * TS + r_db + 8) = h1.v;
  };
  auto load_W1 = [&](int d0) {
    const float* src = Wb + arow * DD + d0 + koff;
    *(float4*)&wx1[0] = *(const float4*)(src);
    *(float4*)&wx1[4] = *(const float4*)(src + 4);
  };
  auto load_RT = [&](int r0) {
#pragma unroll
    for (int g = 0; g < 2; g++) {
      const float* src = Rb + (size_t)(r0 + (rt_rc + 2*g) * 8) * DD + rt_d;
#pragma unroll
      for (int i = 0; i < 8; i++) rx3[8*g + i] = src[i * DD];
    }
  };
  auto stage_RT = [&](int p) {
    U8H h0, h1;
#pragma unroll
    for (int j = 0; j < 4; j++) h0.u[j] = pkh(rx3[2*j],   rx3[2*j+1]);
#pragma unroll
    for (int j = 0; j < 4; j++) h1.u[j] = pkh(rx3[8+2*j], rx3[9+2*j]);
    *(half8*)(SBUF(p) + rt_d * TS + rt_rc * 8)       = h0.v;
    *(half8*)(SBUF(p) + rt_d * TS + (rt_rc + 2) * 8) = h1.v;
  };
  auto load_W4 = [&](int d0) {
    const float* src = Wb + w4row * DD + d0 + w4db;
    *(float4*)&wx4[0] = *(const float4*)(src);
    *(float4*)&wx4[4] = *(const float4*)(src + 4);
  };
  auto stage_W4 = [&](int p) {
    U8H h;
#pragma unroll
    for (int j = 0; j < 4; j++) h.u[j] = pkh(wx4[2*j], wx4[2*j+1]);
    *(half8*)(SBUF(p) + w4row * TS + w4db) = h.v;
  };

  // W hi/lo fp16 split (W represented to ~2^-22): a_h + a_l
  auto cvtW = [&](half8& ah, half8& al) {
    U8H H, L;
#pragma unroll
    for (int j = 0; j < 4; j++) H.u[j] = pkh(wx1[2*j], wx1[2*j+1]);
#pragma unroll
    for (int j = 0; j < 4; j++) {
      float la = wx1[2*j]   - (float)H.v[2*j];
      float lb = wx1[2*j+1] - (float)H.v[2*j+1];
      L.u[j] = pkh(la, lb);
    }
    ah = H.v; al = L.v;
  };

  // issue phase-1 tile-0 loads (hidden under phase 0)
  load_W1(0);
  load_R(0);

  // ---------------- Phase 0: quantile-clipped weights ----------------
  if (tid < 128) {
    float a = Ab[tid];
    qa[tid] = a;
    qs[tid] = (a != 0.0f) ? a : INFINITY;
  }
  __syncthreads();
  for (int k = 2; k <= 128; k <<= 1) {
    for (int j = k >> 1; j > 0; j >>= 1) {
      if (tid < 128) {
        int ixj = tid ^ j;
        if (ixj > tid) {
          float x = qs[tid], y = qs[ixj];
          bool up = ((tid & k) == 0);
          if (up ? (x > y) : (x < y)) { qs[tid] = y; qs[ixj] = x; }
        }
      }
      __syncthreads();
    }
  }
  if (tid < 64) {
    int c = ((qa[lane] != 0.0f) ? 1 : 0) + ((qa[lane + 64] != 0.0f) ? 1 : 0);
#pragma unroll
    for (int m = 1; m < 64; m <<= 1) c += __shfl_xor(c, m, 64);
    if (lane == 0) {
      int nnz = c;
      float low = 0.0f, high = 0.0f;
      if (nnz > 0) {
        float pos = 0.1f * (float)(nnz - 1);
        int lo = (int)floorf(pos), hi = (int)ceilf(pos);
        float frac = pos - floorf(pos);
        low = qs[lo] * (1.0f - frac) + qs[hi] * frac;
        pos = 0.9f * (float)(nnz - 1);
        lo = (int)floorf(pos); hi = (int)ceilf(pos);
        frac = pos - floorf(pos);
        high = qs[lo] * (1.0f - frac) + qs[hi] * frac;
      }
      scal[0] = low; scal[1] = high;
    }
  }
  __syncthreads();
  if (tid < 128) {
    float a = qa[tid];
    qs[tid] = (a != 0.0f) ? fminf(fmaxf(a, scal[0]), scal[1]) : 0.0f;
  }
  __syncthreads();
  if (tid < 64) {
    float s = qs[lane] + qs[lane + 64];
    s = wred_sum(s);
    if (lane == 0) scal[2] = s;
  }
  __syncthreads();
  if (tid < 128) wq[tid] = qs[tid] / scal[2];

  // ---------------- Phase 1: S = W · R^T (fp16: Wh·Rh + Wl·Rh) ----------------
  f32x4 acc[16];
#pragma unroll
  for (int i = 0; i < 16; i++) acc[i] = (f32x4){0.f, 0.f, 0.f, 0.f};

  stage_R(0);
  load_R(32);
  __syncthreads();   // buf0 ready (also covers wq writes)

#pragma unroll 2
  for (int t = 0; t < 8; t++) {
    const int p = t & 1;
    half8 a_h, a_l;
    cvtW(a_h, a_l);
    if (t < 7) {
      stage_R(p ^ 1);
      load_W1((t + 1) * 32);
      if (t < 6) load_R((t + 2) * 32);
    }
    unsigned short* B = SBUF(p);
#pragma unroll
    for (int ct = 0; ct < 16; ct++) {
      half8 b_h = *(const half8*)(B + (16 * ct + l15) * TS + koff);
      acc[ct] = MFMA16(a_h, b_h, acc[ct]);
      acc[ct] = MFMA16(a_l, b_h, acc[ct]);
    }
    __syncthreads();
  }

  // ---------------- Phase 2: softmax in registers -> packed fp16 P ----------------
  load_RT(0);   // prefetch phase-3 tile 0 under softmax
  unsigned int p16u[16][2];
#pragma unroll
  for (int reg = 0; reg < 4; reg++) {
    float mx = acc[0][reg];
#pragma unroll
    for (int ct = 1; ct < 16; ct++) mx = fmaxf(mx, acc[ct][reg]);
    mx = grp16_max(mx);
    float s = 0.f;
#pragma unroll
    for (int ct = 0; ct < 16; ct++) {
      float p = __expf((acc[ct][reg] - mx) * 10.0f);
      acc[ct][reg] = p;
      s += p;
    }
    s = grp16_sum(s);
    float inv = 1.0f / s;
#pragma unroll
    for (int ct = 0; ct < 16; ct++) acc[ct][reg] *= inv;
  }
#pragma unroll
  for (int ct = 0; ct < 16; ct++) {
    p16u[ct][0] = pkh(acc[ct][0], acc[ct][1]);
    p16u[ct][1] = pkh(acc[ct][2], acc[ct][3]);
  }

  // TB write: C-layout chunk (ct pair) -> row-major A tile for one k-tile
#define TB_WRITE(SRC, T, BF)                                              \
  {                                                                       \
    _Pragma("unroll")                                                     \
    for (int e = 0; e < 2; e++) {                                         \
      _Pragma("unroll")                                                   \
      for (int reg = 0; reg < 4; reg++) {                                 \
        unsigned int u = SRC[2 * (T) + e][reg >> 1];                      \
        unsigned short v = (reg & 1) ? (unsigned short)(u >> 16)          \
                                     : (unsigned short)(u & 0xffffu);     \
        TBb[(BF) * 640 + (4 * lg + reg) * TBS + 16 * e + l15] = v;        \
      }                                                                   \
    }                                                                     \
  }

  // ---------------- Phase 3: out = P · R (A from TB, B = R^T fp16-hi) ----------------
#pragma unroll
  for (int i = 0; i < 16; i++) acc[i] = (f32x4){0.f, 0.f, 0.f, 0.f};

  stage_RT(0);
  load_RT(32);
  TB_WRITE(p16u, 0, 0);
  __syncthreads();

#pragma unroll
  for (int t = 0; t < 8; t++) {
    const int p = t & 1;
    if (t < 7) {
      stage_RT(p ^ 1);
      if (t < 6) load_RT((t + 2) * 32);
    }
    half8 pa = *(const half8*)(TBb + p * 640 + l15 * TBS + 8 * lg);
    if (t < 7) TB_WRITE(p16u, t + 1, p ^ 1);
    unsigned short* B = SBUF(p);
#pragma unroll
    for (int ct = 0; ct < 16; ct++) {
      half8 b_h = *(const half8*)(B + (16 * ct + l15) * TS + koff);
      acc[ct] = MFMA16(pa, b_h, acc[ct]);
    }
    __syncthreads();
  }

  // normalize rows in registers, pack out to fp16
  load_W4(0);
#pragma unroll
  for (int reg = 0; reg < 4; reg++) {
    float ss = 0.f;
#pragma unroll
    for (int ct = 0; ct < 16; ct++) { float v = acc[ct][reg]; ss += v * v; }
    ss = grp16_sum(ss);
    float invn = 1.0f / fmaxf(sqrtf(ss), 1e-12f);
#pragma unroll
    for (int ct = 0; ct < 16; ct++) acc[ct][reg] *= invn;
  }
  unsigned int o16u[16][2];
#pragma unroll
  for (int ct = 0; ct < 16; ct++) {
    o16u[ct][0] = pkh(acc[ct][0], acc[ct][1]);
    o16u[ct][1] = pkh(acc[ct][2], acc[ct][3]);
  }

  // ---------------- Phase 4: D[m][n] = out[m]·w[n]  (x10 applied in phase 5) ----------------
#pragma unroll
  for (int i = 0; i < 8; i++) acc[i] = (f32x4){0.f, 0.f, 0.f, 0.f};

  stage_W4(0);
  load_W4(32);
  TB_WRITE(o16u, 0, 0);
  __syncthreads();

#pragma unroll
  for (int t = 0; t < 8; t++) {
    const int p = t & 1;
    if (t < 7) {
      stage_W4(p ^ 1);
      if (t < 6) load_W4((t + 2) * 32);
    }
    half8 oa = *(const half8*)(TBb + p * 640 + l15 * TBS + 8 * lg);
    if (t < 7) TB_WRITE(o16u, t + 1, p ^ 1);
    unsigned short* B = SBUF(p);
#pragma unroll
    for (int ct = 0; ct < 8; ct++) {
      half8 b_h = *(const half8*)(B + (16 * ct + l15) * TS + koff);
      acc[ct] = MFMA16(oa, b_h, acc[ct]);
    }
    __syncthreads();
  }
  // after this barrier, staging region is dead -> PMX/PSM reuse it

  // ---------------- Phase 5: lse + diag + weighted loss, from registers ----------------
  // acc[ct][reg]: D[m][n], m = 16wv + 4lg + reg, n = 16ct + l15; logits = 10*D
  // L2[m] = lse over n (in-lane ct + l15 group)
#pragma unroll
  for (int reg = 0; reg < 4; reg++) {
    float mx = acc[0][reg];
#pragma unroll
    for (int ct = 1; ct < 8; ct++) mx = fmaxf(mx, acc[ct][reg]);
    mx = grp16_max(mx);
    float s = 0.f;
#pragma unroll
    for (int ct = 0; ct < 8; ct++) s += __expf((acc[ct][reg] - mx) * 10.0f);
    s = grp16_sum(s);
    if (l15 == 0) L2[16 * wv + 4 * lg + reg] = 10.0f * mx + __logf(s);
  }
  // diag: n == m  ->  ct == wv, l15 == 4*lg + reg
#pragma unroll
  for (int ct = 0; ct < 8; ct++) {
    if (ct == wv) {
#pragma unroll
      for (int reg = 0; reg < 4; reg++)
        if (l15 == 4 * lg + reg) dgA[16 * wv + l15] = 10.0f * acc[ct][reg];
    }
  }
  // L1 partials: per column n, reduce over this wave's 16 m's (reg in-lane, lg via shfl)
#pragma unroll
  for (int ct = 0; ct < 8; ct++) {
    float m4 = acc[ct][0];
#pragma unroll
    for (int reg = 1; reg < 4; reg++) m4 = fmaxf(m4, acc[ct][reg]);
    m4 = fmaxf(m4, __shfl_xor(m4, 16, 64));
    m4 = fmaxf(m4, __shfl_xor(m4, 32, 64));
    float s4 = 0.f;
#pragma unroll
    for (int reg = 0; reg < 4; reg++) s4 += __expf((acc[ct][reg] - m4) * 10.0f);
    s4 += __shfl_xor(s4, 16, 64);
    s4 += __shfl_xor(s4, 32, 64);
    if (lg == 0) {
      PMX[wv * 128 + 16 * ct + l15] = 10.0f * m4;
      PSM[wv * 128 + 16 * ct + l15] = s4;
    }
  }
  __syncthreads();
  if (tid < 128) {
    float M = PMX[tid];
#pragma unroll
    for (int w = 1; w < 8; w++) M = fmaxf(M, PMX[w * 128 + tid]);
    float s = 0.f;
#pragma unroll
    for (int w = 0; w < 8; w++) s += PSM[w * 128 + tid] * __expf(PMX[w * 128 + tid] - M);
    L1[tid] = M + __logf(s);
  }
  __syncthreads();

  if (tid < 64) {
    float t = 0.0f;
#pragma unroll
    for (int q = 0; q < 2; q++) {
      int k = lane + 64 * q;
      t += wq[k] * (L1[k] + L2[k] - 2.0f * dgA[k]);
    }
    t = wred_sum(t);
    if (lane == 0) partial[b] = t;
  }
}

__global__ void reduce_partials(const float* __restrict__ p, float* __restrict__ out) {
  __shared__ float accw[4];
  int tid = threadIdx.x;
  float t = p[tid] + p[tid + 256];
  t = wred_sum(t);
  if ((tid & 63) == 0) accw[tid >> 6] = t;
  __syncthreads();
  if (tid == 0) out[0] = (accw[0] + accw[1] + accw[2] + accw[3]) * (1.0f / 1024.0f);
}

extern "C" void kernel_launch(void* const* d_in, const int* in_sizes, int n_in,
                              void* d_out, int out_size, void* d_ws, size_t ws_size,
                              hipStream_t stream) {
  const float* region = (const float*)d_in[1];
  const float* word   = (const float*)d_in[3];
  const float* wattn  = (const float*)d_in[4];
  float* out = (float*)d_out;
  float* partial = (float*)d_ws;   // 512 floats

  hipFuncSetAttribute((const void*)wra_fused,
                      hipFuncAttributeMaxDynamicSharedMemorySize, LDS_BYTES);
  hipLaunchKernelGGL(wra_fused, dim3(BZ), dim3(512), LDS_BYTES, stream,
                     region, word, wattn, partial);
  hipLaunchKernelGGL(reduce_partials, dim3(1), dim3(256), 0, stream, partial, out);
}